// Round 2
// baseline (239.237 us; speedup 1.0000x reference)
//
#include <hip/hip_runtime.h>

// One thread per pixel. grid = (HW/256, B). All of v_uvz / mesh_span /
// v_front_mask in the reference is dead code — skipped entirely.
// All float tensors are float32 (per reference dtype); indices int32.
__global__ __launch_bounds__(256) void raster_kernel(
    const float* __restrict__ vertices,    // V*3
    const float* __restrict__ texcoords,   // V*2
    const float* __restrict__ normals,     // V*3
    const int*   __restrict__ f_vt,        // F*3
    const int*   __restrict__ f_vn,        // F*3
    const int*   __restrict__ f_v,         // F*3
    const float* __restrict__ pose,        // B*16
    const float* __restrict__ depth,       // B*HW
    const int*   __restrict__ fim,         // B*HW
    const float* __restrict__ weight,     // B*HW*3
    const float* __restrict__ fuvz,        // B*F*3*3
    float* __restrict__ out,               // B*HW*14
    int F)
{
    const int hw = blockIdx.x * 256 + threadIdx.x;
    const int HW = gridDim.x * 256;
    const int b  = blockIdx.y;
    const int p  = b * HW + hw;

    // Pose (uniform per block; scalar-cached)
    const float* pb = pose + b * 16;
    float R00 = pb[0],  R01 = pb[1],  R02 = pb[2],  t0 = pb[3];
    float R10 = pb[4],  R11 = pb[5],  R12 = pb[6],  t1 = pb[7];
    float R20 = pb[8],  R21 = pb[9],  R22 = pb[10], t2 = pb[11];

    const int   f = fim[p];
    const float d = depth[p];

    // wmap[k] = (1/fz) * weight * depth — exact np f32 op order (uv wraparound!)
    const float* fz = fuvz + ((long)b * F + f) * 9;
    float wm[3];
#pragma unroll
    for (int k = 0; k < 3; ++k) {
        float fzk = fz[k * 3 + 2];
        float w   = weight[(long)p * 3 + k];
        wm[k] = __fmul_rn(__fmul_rn(__fdiv_rn(1.0f, fzk), w), d);
    }

    int ivt[3], ivn[3], iv[3];
#pragma unroll
    for (int k = 0; k < 3; ++k) {
        ivt[k] = f_vt[f * 3 + k];
        ivn[k] = f_vn[f * 3 + k];
        iv[k]  = f_v [f * 3 + k];
    }

    // uv: bit-exact vs numpy ((a0+a1)+a2), no FMA contraction
    float u0t[3], u1t[3];
    float n0 = 0.f, n1 = 0.f, n2 = 0.f;
    float p0 = 0.f, p1 = 0.f, p2 = 0.f;
#pragma unroll
    for (int k = 0; k < 3; ++k) {
        const float* tc = texcoords + (long)ivt[k] * 2;
        u0t[k] = __fmul_rn(tc[0], wm[k]);
        u1t[k] = __fmul_rn(tc[1], wm[k]);
        const float* nr = normals + (long)ivn[k] * 3;
        n0 += nr[0] * wm[k];
        n1 += nr[1] * wm[k];
        n2 += nr[2] * wm[k];
        const float* vv = vertices + (long)iv[k] * 3;
        p0 += vv[0] * wm[k];
        p1 += vv[1] * wm[k];
        p2 += vv[2] * wm[k];
    }
    float uv0 = __fadd_rn(__fadd_rn(u0t[0], u0t[1]), u0t[2]);
    float uv1 = __fadd_rn(__fadd_rn(u1t[0], u1t[1]), u1t[2]);
    uv0 -= floorf(uv0);
    uv1 -= floorf(uv1);

    // normal_map = normalize(n)
    float nn  = sqrtf(n0 * n0 + n1 * n1 + n2 * n2);
    float ni  = 1.0f / fmaxf(nn, 1e-12f);
    float m0 = n0 * ni, m1 = n1 * ni, m2 = n2 * ni;

    // normal_map_cam = normalize(R @ normal_map)
    float c0 = R00 * m0 + R01 * m1 + R02 * m2;
    float c1 = R10 * m0 + R11 * m1 + R12 * m2;
    float c2 = R20 * m0 + R21 * m1 + R22 * m2;
    float cn = sqrtf(c0 * c0 + c1 * c1 + c2 * c2);
    float ci = 1.0f / fmaxf(cn, 1e-12f);
    c0 *= ci; c1 *= ci; c2 *= ci;

    // position_map_cam = R @ p + t
    float q0 = R00 * p0 + R01 * p1 + R02 * p2 + t0;
    float q1 = R10 * p0 + R11 * p1 + R12 * p2 + t1;
    float q2 = R20 * p0 + R21 * p1 + R22 * p2 + t2;

    // out[p, 0:14] = [uv(2), nrm(3), nrm_cam(3), pos(3), pos_cam(3)]
    // byte offset p*56 is 8B-aligned -> 7 float2 stores
    float2* o = (float2*)(out + (long)p * 14);
    o[0] = make_float2(uv0, uv1);
    o[1] = make_float2(m0,  m1);
    o[2] = make_float2(m2,  c0);
    o[3] = make_float2(c1,  c2);
    o[4] = make_float2(p0,  p1);
    o[5] = make_float2(p2,  q0);
    o[6] = make_float2(q1,  q2);
}

extern "C" void kernel_launch(void* const* d_in, const int* in_sizes, int n_in,
                              void* d_out, int out_size, void* d_ws, size_t ws_size,
                              hipStream_t stream) {
    const float* vertices  = (const float*)d_in[0];
    const float* texcoords = (const float*)d_in[1];
    const float* normals   = (const float*)d_in[2];
    const int*   f_vt      = (const int*)  d_in[3];
    const int*   f_vn      = (const int*)  d_in[4];
    const int*   f_v       = (const int*)  d_in[5];
    const float* pose      = (const float*)d_in[6];
    const float* depth     = (const float*)d_in[7];
    const int*   fim       = (const int*)  d_in[8];
    const float* weight    = (const float*)d_in[9];
    // d_in[10] = v_uvz: dead code in the reference — unused
    const float* fuvz      = (const float*)d_in[11];
    float* out = (float*)d_out;

    const int B  = in_sizes[6] / 16;          // pose is B*4*4
    const int F  = in_sizes[3] / 3;           // faces_vt_idx is F*3
    const int HW = in_sizes[7] / B;           // depth is B*H*W

    dim3 grid(HW / 256, B);
    raster_kernel<<<grid, 256, 0, stream>>>(
        vertices, texcoords, normals, f_vt, f_vn, f_v,
        pose, depth, fim, weight, fuvz, out, F);
}

// Round 4
// 193.030 us; speedup vs baseline: 1.2394x; 1.2394x over previous
//
#include <hip/hip_runtime.h>
#include <stdint.h>

// ---------------------------------------------------------------------------
// Round-2 kernel was divergent-transaction-bound: ~20 lane-transactions/pixel
// (132 us ~= 80M transactions / 256CU / 2.4GHz; VALUBusy 3.7%, FETCH 434MB).
// Fast path: precompute per-face records so each pixel does 7 dwordx4 gathers:
//   rec[f]  : 24 floats (tc x3, nrm x3, vtx x3) padded to 128 B
//   fzq[b,f]: {1/fz0, 1/fz1, 1/fz2, 0} as aligned float4 (__fdiv_rn hoisted,
//             bit-identical to computing it in the hot loop)
// All gathered indices are clamped (defense vs round-3 core dump).
// Fallback: proven round-2 single-kernel path if d_ws is unusable.
// ---------------------------------------------------------------------------

// rec layout (floats): [0..5]=t0u,t0v,t1u,t1v,t2u,t2v
//                      [6..14]=n0,n1,n2 (xyz)  [15..23]=v0,v1,v2 (xyz)
__global__ __launch_bounds__(256) void pack_faces(
    const float* __restrict__ tc, const float* __restrict__ nrm,
    const float* __restrict__ vtx,
    const int* __restrict__ f_vt, const int* __restrict__ f_vn,
    const int* __restrict__ f_v,
    float* __restrict__ rec, int F, int V)
{
    int f = blockIdx.x * 256 + threadIdx.x;
    if (f >= F) return;
    float r[24];
#pragma unroll
    for (int k = 0; k < 3; ++k) {
        int ivt = f_vt[f * 3 + k];
        ivt = ivt < 0 ? 0 : (ivt >= V ? V - 1 : ivt);
        r[k * 2 + 0] = tc[(long)ivt * 2 + 0];
        r[k * 2 + 1] = tc[(long)ivt * 2 + 1];
        int ivn = f_vn[f * 3 + k];
        ivn = ivn < 0 ? 0 : (ivn >= V ? V - 1 : ivn);
        r[6 + k * 3 + 0] = nrm[(long)ivn * 3 + 0];
        r[6 + k * 3 + 1] = nrm[(long)ivn * 3 + 1];
        r[6 + k * 3 + 2] = nrm[(long)ivn * 3 + 2];
        int iv = f_v[f * 3 + k];
        iv = iv < 0 ? 0 : (iv >= V ? V - 1 : iv);
        r[15 + k * 3 + 0] = vtx[(long)iv * 3 + 0];
        r[15 + k * 3 + 1] = vtx[(long)iv * 3 + 1];
        r[15 + k * 3 + 2] = vtx[(long)iv * 3 + 2];
    }
    float4* o = (float4*)(rec + (long)f * 32);   // 128-B stride, 16-B aligned
#pragma unroll
    for (int j = 0; j < 6; ++j)
        o[j] = make_float4(r[j * 4], r[j * 4 + 1], r[j * 4 + 2], r[j * 4 + 3]);
}

__global__ __launch_bounds__(256) void pack_fz(
    const float* __restrict__ fuvz, float* __restrict__ fzq, long BF)
{
    long i = (long)blockIdx.x * 256 + threadIdx.x;   // over B*F
    if (i >= BF) return;
    const float* s = fuvz + i * 9;
    ((float4*)fzq)[i] = make_float4(__fdiv_rn(1.0f, s[2]),
                                    __fdiv_rn(1.0f, s[5]),
                                    __fdiv_rn(1.0f, s[8]), 0.0f);
}

__global__ __launch_bounds__(256) void raster_fast(
    const float* __restrict__ rec,     // F*32 floats
    const float* __restrict__ fzq,     // B*F*4 floats (reciprocal fz)
    const float* __restrict__ pose,    // B*16
    const float* __restrict__ depth,   // B*HW
    const int*   __restrict__ fim,     // B*HW
    const float* __restrict__ weight,  // B*HW*3
    float* __restrict__ out,           // B*HW*14
    int F, int HW)
{
    const int hw = blockIdx.x * 256 + threadIdx.x;
    if (hw >= HW) return;
    const int b  = blockIdx.y;
    const int p  = b * HW + hw;

    const float* pb = pose + b * 16;
    float R00 = pb[0],  R01 = pb[1],  R02 = pb[2],  t0 = pb[3];
    float R10 = pb[4],  R11 = pb[5],  R12 = pb[6],  t1 = pb[7];
    float R20 = pb[8],  R21 = pb[9],  R22 = pb[10], t2 = pb[11];

    int f = fim[p];
    f = f < 0 ? 0 : (f >= F ? F - 1 : f);
    const float d = depth[p];
    float w0 = weight[(long)p * 3 + 0];
    float w1 = weight[(long)p * 3 + 1];
    float w2 = weight[(long)p * 3 + 2];

    // 7 divergent dwordx4 gathers total:
    const float4* R4 = (const float4*)(rec + (long)f * 32);
    float4 a0 = R4[0], a1 = R4[1], a2 = R4[2], a3 = R4[3], a4 = R4[4], a5 = R4[5];
    float4 fz = ((const float4*)fzq)[(long)b * F + f];

    // wm[k] = ((1/fz)*w)*d — exact np f32 op order (uv wraparound sensitivity);
    // fz.{x,y,z} already hold __fdiv_rn(1,fz)
    float wm0 = __fmul_rn(__fmul_rn(fz.x, w0), d);
    float wm1 = __fmul_rn(__fmul_rn(fz.y, w1), d);
    float wm2 = __fmul_rn(__fmul_rn(fz.z, w2), d);

    // uv: bit-exact vs numpy ((a0+a1)+a2), no FMA contraction
    float uv0 = __fadd_rn(__fadd_rn(__fmul_rn(a0.x, wm0), __fmul_rn(a0.z, wm1)),
                          __fmul_rn(a1.x, wm2));
    float uv1 = __fadd_rn(__fadd_rn(__fmul_rn(a0.y, wm0), __fmul_rn(a0.w, wm1)),
                          __fmul_rn(a1.y, wm2));
    uv0 -= floorf(uv0);
    uv1 -= floorf(uv1);

    // normals: n0=(a1.z,a1.w,a2.x) n1=(a2.y,a2.z,a2.w) n2=(a3.x,a3.y,a3.z)
    float n0 = a1.z * wm0 + a2.y * wm1 + a3.x * wm2;
    float n1 = a1.w * wm0 + a2.z * wm1 + a3.y * wm2;
    float n2 = a2.x * wm0 + a2.w * wm1 + a3.z * wm2;

    // vertices: v0=(a3.w,a4.x,a4.y) v1=(a4.z,a4.w,a5.x) v2=(a5.y,a5.z,a5.w)
    float p0 = a3.w * wm0 + a4.z * wm1 + a5.y * wm2;
    float p1 = a4.x * wm0 + a4.w * wm1 + a5.z * wm2;
    float p2 = a4.y * wm0 + a5.x * wm1 + a5.w * wm2;

    float nn = sqrtf(n0 * n0 + n1 * n1 + n2 * n2);
    float ni = 1.0f / fmaxf(nn, 1e-12f);
    float m0 = n0 * ni, m1 = n1 * ni, m2 = n2 * ni;

    float c0 = R00 * m0 + R01 * m1 + R02 * m2;
    float c1 = R10 * m0 + R11 * m1 + R12 * m2;
    float c2 = R20 * m0 + R21 * m1 + R22 * m2;
    float cn = sqrtf(c0 * c0 + c1 * c1 + c2 * c2);
    float ci = 1.0f / fmaxf(cn, 1e-12f);
    c0 *= ci; c1 *= ci; c2 *= ci;

    float q0 = R00 * p0 + R01 * p1 + R02 * p2 + t0;
    float q1 = R10 * p0 + R11 * p1 + R12 * p2 + t1;
    float q2 = R20 * p0 + R21 * p1 + R22 * p2 + t2;

    float2* o = (float2*)(out + (long)p * 14);
    o[0] = make_float2(uv0, uv1);
    o[1] = make_float2(m0,  m1);
    o[2] = make_float2(m2,  c0);
    o[3] = make_float2(c1,  c2);
    o[4] = make_float2(p0,  p1);
    o[5] = make_float2(p2,  q0);
    o[6] = make_float2(q1,  q2);
}

// ---- fallback: the proven round-2 single-kernel path -----------------------
__global__ __launch_bounds__(256) void raster_kernel(
    const float* __restrict__ vertices, const float* __restrict__ texcoords,
    const float* __restrict__ normals,
    const int* __restrict__ f_vt, const int* __restrict__ f_vn,
    const int* __restrict__ f_v,
    const float* __restrict__ pose, const float* __restrict__ depth,
    const int* __restrict__ fim, const float* __restrict__ weight,
    const float* __restrict__ fuvz, float* __restrict__ out, int F, int V)
{
    const int hw = blockIdx.x * 256 + threadIdx.x;
    const int HW = gridDim.x * 256;
    const int b  = blockIdx.y;
    const int p  = b * HW + hw;
    const float* pb = pose + b * 16;
    float R00 = pb[0], R01 = pb[1], R02 = pb[2],  t0 = pb[3];
    float R10 = pb[4], R11 = pb[5], R12 = pb[6],  t1 = pb[7];
    float R20 = pb[8], R21 = pb[9], R22 = pb[10], t2 = pb[11];
    int f = fim[p];
    f = f < 0 ? 0 : (f >= F ? F - 1 : f);
    const float d = depth[p];
    const float* fz = fuvz + ((long)b * F + f) * 9;
    float wm[3];
#pragma unroll
    for (int k = 0; k < 3; ++k)
        wm[k] = __fmul_rn(__fmul_rn(__fdiv_rn(1.0f, fz[k * 3 + 2]),
                                    weight[(long)p * 3 + k]), d);
    float u0t[3], u1t[3];
    float n0 = 0.f, n1 = 0.f, n2 = 0.f, p0 = 0.f, p1 = 0.f, p2 = 0.f;
#pragma unroll
    for (int k = 0; k < 3; ++k) {
        int ivt = f_vt[f * 3 + k], ivn = f_vn[f * 3 + k], iv = f_v[f * 3 + k];
        ivt = ivt < 0 ? 0 : (ivt >= V ? V - 1 : ivt);
        ivn = ivn < 0 ? 0 : (ivn >= V ? V - 1 : ivn);
        iv  = iv  < 0 ? 0 : (iv  >= V ? V - 1 : iv);
        const float* tc = texcoords + (long)ivt * 2;
        u0t[k] = __fmul_rn(tc[0], wm[k]);
        u1t[k] = __fmul_rn(tc[1], wm[k]);
        const float* nr = normals + (long)ivn * 3;
        n0 += nr[0] * wm[k]; n1 += nr[1] * wm[k]; n2 += nr[2] * wm[k];
        const float* vv = vertices + (long)iv * 3;
        p0 += vv[0] * wm[k]; p1 += vv[1] * wm[k]; p2 += vv[2] * wm[k];
    }
    float uv0 = __fadd_rn(__fadd_rn(u0t[0], u0t[1]), u0t[2]);
    float uv1 = __fadd_rn(__fadd_rn(u1t[0], u1t[1]), u1t[2]);
    uv0 -= floorf(uv0); uv1 -= floorf(uv1);
    float nn = sqrtf(n0 * n0 + n1 * n1 + n2 * n2);
    float ni = 1.0f / fmaxf(nn, 1e-12f);
    float m0 = n0 * ni, m1 = n1 * ni, m2 = n2 * ni;
    float c0 = R00 * m0 + R01 * m1 + R02 * m2;
    float c1 = R10 * m0 + R11 * m1 + R12 * m2;
    float c2 = R20 * m0 + R21 * m1 + R22 * m2;
    float cn = sqrtf(c0 * c0 + c1 * c1 + c2 * c2);
    float ci = 1.0f / fmaxf(cn, 1e-12f);
    c0 *= ci; c1 *= ci; c2 *= ci;
    float q0 = R00 * p0 + R01 * p1 + R02 * p2 + t0;
    float q1 = R10 * p0 + R11 * p1 + R12 * p2 + t1;
    float q2 = R20 * p0 + R21 * p1 + R22 * p2 + t2;
    float2* o = (float2*)(out + (long)p * 14);
    o[0] = make_float2(uv0, uv1); o[1] = make_float2(m0, m1);
    o[2] = make_float2(m2, c0);   o[3] = make_float2(c1, c2);
    o[4] = make_float2(p0, p1);   o[5] = make_float2(p2, q0);
    o[6] = make_float2(q1, q2);
}

extern "C" void kernel_launch(void* const* d_in, const int* in_sizes, int n_in,
                              void* d_out, int out_size, void* d_ws, size_t ws_size,
                              hipStream_t stream) {
    const float* vertices  = (const float*)d_in[0];
    const float* texcoords = (const float*)d_in[1];
    const float* normals   = (const float*)d_in[2];
    const int*   f_vt      = (const int*)  d_in[3];
    const int*   f_vn      = (const int*)  d_in[4];
    const int*   f_v       = (const int*)  d_in[5];
    const float* pose      = (const float*)d_in[6];
    const float* depth     = (const float*)d_in[7];
    const int*   fim       = (const int*)  d_in[8];
    const float* weight    = (const float*)d_in[9];
    const float* fuvz      = (const float*)d_in[11];   // d_in[10] v_uvz: dead
    float* out = (float*)d_out;

    const int B  = in_sizes[6] / 16;
    const int F  = in_sizes[3] / 3;
    const int V  = in_sizes[1] / 2;
    const int HW = in_sizes[7] / B;

    const size_t rec_bytes = (size_t)F * 128;           // 25.6 MB
    const size_t fzq_bytes = (size_t)B * F * 16;        // 12.8 MB
    const bool ws_ok = d_ws != nullptr &&
                       ws_size >= rec_bytes + fzq_bytes &&
                       (((uintptr_t)d_ws) & 15) == 0;

    if (ws_ok) {
        float* rec = (float*)d_ws;
        float* fzq = (float*)((char*)d_ws + rec_bytes);
        long BF = (long)B * F;
        pack_faces<<<(F + 255) / 256, 256, 0, stream>>>(
            texcoords, normals, vertices, f_vt, f_vn, f_v, rec, F, V);
        pack_fz<<<(unsigned)((BF + 255) / 256), 256, 0, stream>>>(fuvz, fzq, BF);
        dim3 grid((HW + 255) / 256, B);
        raster_fast<<<grid, 256, 0, stream>>>(
            rec, fzq, pose, depth, fim, weight, out, F, HW);
    } else {
        dim3 grid(HW / 256, B);
        raster_kernel<<<grid, 256, 0, stream>>>(
            vertices, texcoords, normals, f_vt, f_vn, f_v,
            pose, depth, fim, weight, fuvz, out, F, V);
    }
}

// Round 5
// 176.664 us; speedup vs baseline: 1.3542x; 1.0926x over previous
//
#include <hip/hip_runtime.h>
#include <stdint.h>

// ---------------------------------------------------------------------------
// Bottleneck model (rounds 2->4): time ~ divergent line-requests/pixel x ~4.5cy.
// R4: 7 gather dwordx4 + ~6 store line-splits = 55 us. This round:
//   - rec[f] shrunk 128B -> 64B: tc stays f32 (uv frac() must stay bit-exact
//     vs numpy), normals+vertices stored fp16 (feed normalize/rotate only;
//     abs err ~0.04 << 0.3425 threshold)  => 4 rec gathers + 1 fzq gather
//   - LDS-staged output: block writes 14336 B contiguously as float4
//     => store line-requests ~6/pixel -> ~0.9/pixel
// Fallback: proven round-2 single-kernel path if d_ws unusable.
// ---------------------------------------------------------------------------

struct H2 { _Float16 x, y; };
static __device__ __forceinline__ float packh(float a, float b) {
    H2 h; h.x = (_Float16)a; h.y = (_Float16)b;
    return __builtin_bit_cast(float, h);
}
static __device__ __forceinline__ float2 unph(float w) {
    H2 h = __builtin_bit_cast(H2, w);
    return make_float2((float)h.x, (float)h.y);
}

// rec: 16 floats/face (64 B): [0..5] tc f32; words 6..14 = 18 halfs
// (nrm0..nrm8, vtx0..vtx8); word 15 pad.
__global__ __launch_bounds__(256) void pack_faces(
    const float* __restrict__ tc, const float* __restrict__ nrm,
    const float* __restrict__ vtx,
    const int* __restrict__ f_vt, const int* __restrict__ f_vn,
    const int* __restrict__ f_v,
    float* __restrict__ rec, int F, int V)
{
    int f = blockIdx.x * 256 + threadIdx.x;
    if (f >= F) return;
    float w[16];
    float h[18];
#pragma unroll
    for (int k = 0; k < 3; ++k) {
        int ivt = f_vt[f * 3 + k];
        ivt = ivt < 0 ? 0 : (ivt >= V ? V - 1 : ivt);
        w[k * 2 + 0] = tc[(long)ivt * 2 + 0];
        w[k * 2 + 1] = tc[(long)ivt * 2 + 1];
        int ivn = f_vn[f * 3 + k];
        ivn = ivn < 0 ? 0 : (ivn >= V ? V - 1 : ivn);
        h[k * 3 + 0] = nrm[(long)ivn * 3 + 0];
        h[k * 3 + 1] = nrm[(long)ivn * 3 + 1];
        h[k * 3 + 2] = nrm[(long)ivn * 3 + 2];
        int iv = f_v[f * 3 + k];
        iv = iv < 0 ? 0 : (iv >= V ? V - 1 : iv);
        h[9 + k * 3 + 0] = vtx[(long)iv * 3 + 0];
        h[9 + k * 3 + 1] = vtx[(long)iv * 3 + 1];
        h[9 + k * 3 + 2] = vtx[(long)iv * 3 + 2];
    }
#pragma unroll
    for (int j = 0; j < 9; ++j)
        w[6 + j] = packh(h[2 * j], h[2 * j + 1]);
    w[15] = 0.0f;
    float4* o = (float4*)(rec + (long)f * 16);   // 64-B stride
#pragma unroll
    for (int j = 0; j < 4; ++j)
        o[j] = make_float4(w[j * 4], w[j * 4 + 1], w[j * 4 + 2], w[j * 4 + 3]);
}

__global__ __launch_bounds__(256) void pack_fz(
    const float* __restrict__ fuvz, float* __restrict__ fzq, long BF)
{
    long i = (long)blockIdx.x * 256 + threadIdx.x;   // over B*F
    if (i >= BF) return;
    const float* s = fuvz + i * 9;
    ((float4*)fzq)[i] = make_float4(__fdiv_rn(1.0f, s[2]),
                                    __fdiv_rn(1.0f, s[5]),
                                    __fdiv_rn(1.0f, s[8]), 0.0f);
}

// Requires HW % 256 == 0 (enforced in launcher; needed for __syncthreads).
__global__ __launch_bounds__(256) void raster_fast(
    const float* __restrict__ rec,     // F*16 floats (64 B/face)
    const float* __restrict__ fzq,     // B*F*4 floats (reciprocal fz)
    const float* __restrict__ pose,    // B*16
    const float* __restrict__ depth,   // B*HW
    const int*   __restrict__ fim,     // B*HW
    const float* __restrict__ weight,  // B*HW*3
    float* __restrict__ out,           // B*HW*14
    int F, int HW)
{
    __shared__ float sb[256 * 14];
    const int tid = threadIdx.x;
    const int hw  = blockIdx.x * 256 + tid;
    const int b   = blockIdx.y;
    const int p   = b * HW + hw;

    const float* pb = pose + b * 16;
    float R00 = pb[0],  R01 = pb[1],  R02 = pb[2],  t0 = pb[3];
    float R10 = pb[4],  R11 = pb[5],  R12 = pb[6],  t1 = pb[7];
    float R20 = pb[8],  R21 = pb[9],  R22 = pb[10], t2 = pb[11];

    int f = fim[p];
    f = f < 0 ? 0 : (f >= F ? F - 1 : f);
    const float d = depth[p];
    float w0 = weight[(long)p * 3 + 0];
    float w1 = weight[(long)p * 3 + 1];
    float w2 = weight[(long)p * 3 + 2];

    // 5 divergent dwordx4 gathers total (4 rec + 1 fzq):
    const float4* R4 = (const float4*)(rec + (long)f * 16);
    float4 a0 = R4[0], a1 = R4[1], a2 = R4[2], a3 = R4[3];
    float4 fz = ((const float4*)fzq)[(long)b * F + f];

    // wm[k] = ((1/fz)*w)*d — exact np f32 op order (uv wrap sensitivity);
    // fz.{x,y,z} already hold __fdiv_rn(1,fz) (hoisted, bit-identical)
    float wm0 = __fmul_rn(__fmul_rn(fz.x, w0), d);
    float wm1 = __fmul_rn(__fmul_rn(fz.y, w1), d);
    float wm2 = __fmul_rn(__fmul_rn(fz.z, w2), d);

    // uv: bit-exact vs numpy ((a0+a1)+a2), no FMA contraction
    float uv0 = __fadd_rn(__fadd_rn(__fmul_rn(a0.x, wm0), __fmul_rn(a0.z, wm1)),
                          __fmul_rn(a1.x, wm2));
    float uv1 = __fadd_rn(__fadd_rn(__fmul_rn(a0.y, wm0), __fmul_rn(a0.w, wm1)),
                          __fmul_rn(a1.y, wm2));
    uv0 -= floorf(uv0);
    uv1 -= floorf(uv1);

    // 18 halfs: nrm[0..8], vtx[0..8]
    float2 g0 = unph(a1.z), g1 = unph(a1.w), g2 = unph(a2.x);
    float2 g3 = unph(a2.y), g4 = unph(a2.z), g5 = unph(a2.w);
    float2 g6 = unph(a3.x), g7 = unph(a3.y), g8 = unph(a3.z);
    // nrm: n0=(g0.x,g0.y,g1.x) n1=(g1.y,g2.x,g2.y) n2=(g3.x,g3.y,g4.x)
    float n0 = g0.x * wm0 + g1.y * wm1 + g3.x * wm2;
    float n1 = g0.y * wm0 + g2.x * wm1 + g3.y * wm2;
    float n2 = g1.x * wm0 + g2.y * wm1 + g4.x * wm2;
    // vtx: v0=(g4.y,g5.x,g5.y) v1=(g6.x,g6.y,g7.x) v2=(g7.y,g8.x,g8.y)
    float p0 = g4.y * wm0 + g6.x * wm1 + g7.y * wm2;
    float p1 = g5.x * wm0 + g6.y * wm1 + g8.x * wm2;
    float p2 = g5.y * wm0 + g7.x * wm1 + g8.y * wm2;

    float nn = sqrtf(n0 * n0 + n1 * n1 + n2 * n2);
    float ni = 1.0f / fmaxf(nn, 1e-12f);
    float m0 = n0 * ni, m1 = n1 * ni, m2 = n2 * ni;

    float c0 = R00 * m0 + R01 * m1 + R02 * m2;
    float c1 = R10 * m0 + R11 * m1 + R12 * m2;
    float c2 = R20 * m0 + R21 * m1 + R22 * m2;
    float cn = sqrtf(c0 * c0 + c1 * c1 + c2 * c2);
    float ci = 1.0f / fmaxf(cn, 1e-12f);
    c0 *= ci; c1 *= ci; c2 *= ci;

    float q0 = R00 * p0 + R01 * p1 + R02 * p2 + t0;
    float q1 = R10 * p0 + R11 * p1 + R12 * p2 + t1;
    float q2 = R20 * p0 + R21 * p1 + R22 * p2 + t2;

    // stage 14 channels in LDS, then stream the block's 14336 B coalesced
    float* s = sb + tid * 14;
    s[0]  = uv0; s[1]  = uv1;
    s[2]  = m0;  s[3]  = m1;  s[4]  = m2;
    s[5]  = c0;  s[6]  = c1;  s[7]  = c2;
    s[8]  = p0;  s[9]  = p1;  s[10] = p2;
    s[11] = q0;  s[12] = q1;  s[13] = q2;
    __syncthreads();

    float4* og = (float4*)(out + ((long)b * HW + (long)blockIdx.x * 256) * 14);
    const float4* sv = (const float4*)sb;
#pragma unroll
    for (int j = 0; j < 4; ++j) {
        int k = tid + 256 * j;
        if (k < 896) og[k] = sv[k];
    }
}

// ---- fallback: the proven round-2 single-kernel path -----------------------
__global__ __launch_bounds__(256) void raster_kernel(
    const float* __restrict__ vertices, const float* __restrict__ texcoords,
    const float* __restrict__ normals,
    const int* __restrict__ f_vt, const int* __restrict__ f_vn,
    const int* __restrict__ f_v,
    const float* __restrict__ pose, const float* __restrict__ depth,
    const int* __restrict__ fim, const float* __restrict__ weight,
    const float* __restrict__ fuvz, float* __restrict__ out, int F, int V,
    int HW)
{
    const int hw = blockIdx.x * 256 + threadIdx.x;
    if (hw >= HW) return;
    const int b  = blockIdx.y;
    const int p  = b * HW + hw;
    const float* pb = pose + b * 16;
    float R00 = pb[0], R01 = pb[1], R02 = pb[2],  t0 = pb[3];
    float R10 = pb[4], R11 = pb[5], R12 = pb[6],  t1 = pb[7];
    float R20 = pb[8], R21 = pb[9], R22 = pb[10], t2 = pb[11];
    int f = fim[p];
    f = f < 0 ? 0 : (f >= F ? F - 1 : f);
    const float d = depth[p];
    const float* fz = fuvz + ((long)b * F + f) * 9;
    float wm[3];
#pragma unroll
    for (int k = 0; k < 3; ++k)
        wm[k] = __fmul_rn(__fmul_rn(__fdiv_rn(1.0f, fz[k * 3 + 2]),
                                    weight[(long)p * 3 + k]), d);
    float u0t[3], u1t[3];
    float n0 = 0.f, n1 = 0.f, n2 = 0.f, p0 = 0.f, p1 = 0.f, p2 = 0.f;
#pragma unroll
    for (int k = 0; k < 3; ++k) {
        int ivt = f_vt[f * 3 + k], ivn = f_vn[f * 3 + k], iv = f_v[f * 3 + k];
        ivt = ivt < 0 ? 0 : (ivt >= V ? V - 1 : ivt);
        ivn = ivn < 0 ? 0 : (ivn >= V ? V - 1 : ivn);
        iv  = iv  < 0 ? 0 : (iv  >= V ? V - 1 : iv);
        const float* tc = texcoords + (long)ivt * 2;
        u0t[k] = __fmul_rn(tc[0], wm[k]);
        u1t[k] = __fmul_rn(tc[1], wm[k]);
        const float* nr = normals + (long)ivn * 3;
        n0 += nr[0] * wm[k]; n1 += nr[1] * wm[k]; n2 += nr[2] * wm[k];
        const float* vv = vertices + (long)iv * 3;
        p0 += vv[0] * wm[k]; p1 += vv[1] * wm[k]; p2 += vv[2] * wm[k];
    }
    float uv0 = __fadd_rn(__fadd_rn(u0t[0], u0t[1]), u0t[2]);
    float uv1 = __fadd_rn(__fadd_rn(u1t[0], u1t[1]), u1t[2]);
    uv0 -= floorf(uv0); uv1 -= floorf(uv1);
    float nn = sqrtf(n0 * n0 + n1 * n1 + n2 * n2);
    float ni = 1.0f / fmaxf(nn, 1e-12f);
    float m0 = n0 * ni, m1 = n1 * ni, m2 = n2 * ni;
    float c0 = R00 * m0 + R01 * m1 + R02 * m2;
    float c1 = R10 * m0 + R11 * m1 + R12 * m2;
    float c2 = R20 * m0 + R21 * m1 + R22 * m2;
    float cn = sqrtf(c0 * c0 + c1 * c1 + c2 * c2);
    float ci = 1.0f / fmaxf(cn, 1e-12f);
    c0 *= ci; c1 *= ci; c2 *= ci;
    float q0 = R00 * p0 + R01 * p1 + R02 * p2 + t0;
    float q1 = R10 * p0 + R11 * p1 + R12 * p2 + t1;
    float q2 = R20 * p0 + R21 * p1 + R22 * p2 + t2;
    float2* o = (float2*)(out + (long)p * 14);
    o[0] = make_float2(uv0, uv1); o[1] = make_float2(m0, m1);
    o[2] = make_float2(m2, c0);   o[3] = make_float2(c1, c2);
    o[4] = make_float2(p0, p1);   o[5] = make_float2(p2, q0);
    o[6] = make_float2(q1, q2);
}

extern "C" void kernel_launch(void* const* d_in, const int* in_sizes, int n_in,
                              void* d_out, int out_size, void* d_ws, size_t ws_size,
                              hipStream_t stream) {
    const float* vertices  = (const float*)d_in[0];
    const float* texcoords = (const float*)d_in[1];
    const float* normals   = (const float*)d_in[2];
    const int*   f_vt      = (const int*)  d_in[3];
    const int*   f_vn      = (const int*)  d_in[4];
    const int*   f_v       = (const int*)  d_in[5];
    const float* pose      = (const float*)d_in[6];
    const float* depth     = (const float*)d_in[7];
    const int*   fim       = (const int*)  d_in[8];
    const float* weight    = (const float*)d_in[9];
    const float* fuvz      = (const float*)d_in[11];   // d_in[10] v_uvz: dead
    float* out = (float*)d_out;

    const int B  = in_sizes[6] / 16;
    const int F  = in_sizes[3] / 3;
    const int V  = in_sizes[1] / 2;
    const int HW = in_sizes[7] / B;

    const size_t rec_bytes = (size_t)F * 64;            // 12.8 MB
    const size_t fzq_bytes = (size_t)B * F * 16;        // 12.8 MB
    const bool ws_ok = d_ws != nullptr &&
                       ws_size >= rec_bytes + fzq_bytes &&
                       (((uintptr_t)d_ws) & 15) == 0 &&
                       (HW % 256) == 0;

    if (ws_ok) {
        float* rec = (float*)d_ws;
        float* fzq = (float*)((char*)d_ws + rec_bytes);
        long BF = (long)B * F;
        pack_faces<<<(F + 255) / 256, 256, 0, stream>>>(
            texcoords, normals, vertices, f_vt, f_vn, f_v, rec, F, V);
        pack_fz<<<(unsigned)((BF + 255) / 256), 256, 0, stream>>>(fuvz, fzq, BF);
        dim3 grid(HW / 256, B);
        raster_fast<<<grid, 256, 0, stream>>>(
            rec, fzq, pose, depth, fim, weight, out, F, HW);
    } else {
        dim3 grid((HW + 255) / 256, B);
        raster_kernel<<<grid, 256, 0, stream>>>(
            vertices, texcoords, normals, f_vt, f_vn, f_v,
            pose, depth, fim, weight, fuvz, out, F, V, HW);
    }
}